// Round 11
// baseline (3394.517 us; speedup 1.0000x reference)
//
#include <hip/hip_runtime.h>

// Echo-state RNN, B=32, T=2048, NH=512.  W_hh ~90% exact zeros.
// One workgroup (CU) per batch; thread p owns row perm[p], rows sorted by nnz
// desc. Gather slots from EDGE-MAJOR FIRST-FIT coloring per (wave, half):
// each edge (lane,bank,mult) placed at the lowest color free at both
// endpoints (else lowest lane-free color -- validity by construction, no
// repair pass; r10's augmenting-path version silently degraded). Slot count
// ~= Delta ~= 55..82 per wave AND near-zero bank conflicts. esn_steps is
// round-7's kernel with __launch_bounds__(512,1): the old (512,2) capped
// VGPR at 128 and forced per-step L2 streaming of the weight tail; only 32
// blocks exist so 1 block/CU costs nothing. 88 slots pinned (176 VGPRs).

#define NH   512
#define TT   2048
#define BB   32
#define PAD  96
#define PIN  88
#define NONE_ 0xFF

// ---------------------------------------------------------------------------
// A: nnz per row (wave-per-row ballot count)
// ---------------------------------------------------------------------------
__global__ __launch_bounds__(512) void count_nnz(
    const float* __restrict__ Whh, int* __restrict__ nnz) {
  const int wib  = threadIdx.x >> 6;
  const int lane = threadIdx.x & 63;
  const int row  = blockIdx.x * 8 + wib;
  const float* wrow = Whh + (size_t)row * NH;
  int cnt = 0;
  for (int c = 0; c < NH / 64; ++c)
    cnt += __popcll(__ballot(wrow[c * 64 + lane] != 0.0f));
  if (lane == 0) nnz[row] = cnt;
}

// ---------------------------------------------------------------------------
// B: rank rows by nnz descending (stable). perm[p] = row at sorted pos p.
// ---------------------------------------------------------------------------
__global__ __launch_bounds__(512) void sort_rows(
    const int* __restrict__ nnz, int* __restrict__ perm) {
  __shared__ int nl[NH];
  const int j = threadIdx.x;
  const int my = nnz[j];
  nl[j] = my;
  __syncthreads();
  int r = 0;
  const int4* p4 = (const int4*)nl;
  for (int i = 0; i < NH / 4; ++i) {
    int4 v = p4[i];
    const int base = i * 4;
    r += (v.x > my) || (v.x == my && base + 0 < j);
    r += (v.y > my) || (v.y == my && base + 1 < j);
    r += (v.z > my) || (v.z == my && base + 2 < j);
    r += (v.w > my) || (v.w == my && base + 3 < j);
  }
  perm[r] = j;
}

// ---------------------------------------------------------------------------
// C: first-fit edge coloring per (wave, half). Block = wave g (grid 8,
// 64 thr). Lanes 0 and 32 are the half-workers; all 64 threads load occ and
// write the schedule. Edge (lane,bank) x multiplicity -> lowest color free
// at both endpoints; fallback lowest lane-free color (always exists:
// deg <= ~80 < 96). Valid by construction: every entry placed exactly once,
// per-lane colors distinct.
// ---------------------------------------------------------------------------
__global__ __launch_bounds__(64) void build_sched(
    const float* __restrict__ Whh, const int* __restrict__ perm,
    float* __restrict__ vals, unsigned* __restrict__ offs,
    int* __restrict__ cntw) {
  __shared__ unsigned short occ[64][32];     // per-lane per-bank presence bits
  __shared__ unsigned char  sb[64][PAD];     // slot -> bank (or NONE_)
  __shared__ unsigned freeL[2][32][3];       // 96-bit free-color masks
  __shared__ unsigned freeB[2][32][3];
  __shared__ int cwsh;

  const int lane = threadIdx.x;
  const int g    = blockIdx.x;
  const int p    = g * 64 + lane;
  const int hl   = lane >> 5;
  const int li   = lane & 31;
  const int row  = perm[p];
  const float* wrow = Whh + (size_t)row * NH;

  if (lane == 0) cwsh = 0;
  for (int b = 0; b < 32; ++b) {
    unsigned m16 = 0;
    for (int m = 0; m < 16; ++m)
      m16 |= (wrow[b + 32 * m] != 0.f) ? (1u << m) : 0u;
    occ[lane][b] = (unsigned short)m16;
  }
  for (int c = 0; c < PAD; ++c) sb[lane][c] = NONE_;
  #pragma unroll
  for (int w2 = 0; w2 < 3; ++w2) {
    freeL[hl][li][w2] = 0xFFFFFFFFu;
    freeB[hl][li][w2] = 0xFFFFFFFFu;
  }
  __syncthreads();

  if (li == 0) {                             // workers: lanes 0 and 32
    int maxc = 0;
    for (int l = 0; l < 32; ++l) {
      const int gl = hl * 32 + l;
      for (int b = 0; b < 32; ++b) {
        const int mult = __popc((unsigned)occ[gl][b]);
        for (int m = 0; m < mult; ++m) {
          int c = -1;
          #pragma unroll
          for (int w2 = 0; w2 < 3; ++w2) {
            unsigned cm = freeL[hl][l][w2] & freeB[hl][b][w2];
            if (cm) { c = w2 * 32 + __ffs(cm) - 1; break; }
          }
          const bool common = (c >= 0);
          if (!common) {                     // rare: accept one conflict
            #pragma unroll
            for (int w2 = 0; w2 < 3; ++w2) {
              unsigned lm = freeL[hl][l][w2];
              if (c < 0 && lm) c = w2 * 32 + __ffs(lm) - 1;
            }
          }
          sb[gl][c] = (unsigned char)b;
          freeL[hl][l][c >> 5] &= ~(1u << (c & 31));
          if (common) freeB[hl][b][c >> 5] &= ~(1u << (c & 31));
          if (c > maxc) maxc = c;
        }
      }
    }
    atomicMax(&cwsh, maxc + 1);
  }
  __syncthreads();
  if (lane == 0) cntw[g] = cwsh;

  // write phase: slot c -> consume lowest remaining column of matched bank.
  for (int c = 0; c < PAD; ++c) {
    int b = sb[lane][c];
    float v = 0.f; unsigned col = 0u;
    if (b != NONE_) {
      unsigned m16 = (unsigned)occ[lane][b];
      int m = __ffs(m16) - 1;
      occ[lane][b] = (unsigned short)(m16 & (m16 - 1u));
      col = (unsigned)(b + 32 * m);
      v = wrow[col];
    }
    vals[c * NH + p] = v;
    offs[c * NH + p] = col;
  }
}

// ---------------------------------------------------------------------------
// DPP wave-64 sum reduction on the VALU pipe; lane 63 ends with the full sum.
// ---------------------------------------------------------------------------
template <int CTRL, int RM>
__device__ __forceinline__ float dppadd(float v) {
  int t = __builtin_amdgcn_update_dpp(0, __float_as_int(v), CTRL, RM, 0xF, true);
  return v + __int_as_float(t);
}
__device__ __forceinline__ float wave_sum_lane63(float v) {
  v = dppadd<0xB1,  0xF>(v);
  v = dppadd<0x4E,  0xF>(v);
  v = dppadd<0x141, 0xF>(v);
  v = dppadd<0x140, 0xF>(v);
  v = dppadd<0x142, 0xA>(v);
  v = dppadd<0x143, 0xC>(v);
  return v;
}

// fast tanh: (t-1)/(t+1), t = exp(2x), clamp |x|<=9.
__device__ __forceinline__ float ftanh(float x) {
  float xc = fminf(9.0f, fmaxf(-9.0f, x));
  float t  = __expf(2.0f * xc);
  return (t - 1.0f) * __builtin_amdgcn_rcpf(t + 1.0f);
}

// ---------------------------------------------------------------------------
// Main: one block per batch, 512 threads, 2048 sequential steps (x2 unroll).
// Round-7 structure; launch_bounds (512,1) for the full 256-VGPR budget.
// ---------------------------------------------------------------------------
#define GA(T_RD, E) (*(const float*)((const char*)(T_RD) + cidx[E]))

#define ESN_STEP(T_RD, T_WR, RWR, SIDX)                                      \
  {                                                                          \
    float d0 = 0.f, d1 = 0.f, d2 = 0.f, d3 = 0.f;                            \
    _Pragma("unroll")                                                        \
    for (int e = 0; e < PAD; e += 4) {                                       \
      if (e < cw) {                                                          \
        d0 = fmaf(wval[e + 0], GA(T_RD, e + 0), d0);                         \
        d1 = fmaf(wval[e + 1], GA(T_RD, e + 1), d1);                         \
        d2 = fmaf(wval[e + 2], GA(T_RD, e + 2), d2);                         \
        d3 = fmaf(wval[e + 3], GA(T_RD, e + 3), d3);                         \
      }                                                                      \
    }                                                                        \
    float dot  = (d0 + d1) + (d2 + d3);                                      \
    float xp   = x_lds[SIDX] * w_ih;                                         \
    float dhdt = ((dot - h) + xp) + z_prev * w_zh;                           \
    float hn   = h + 0.1f * dhdt;                                            \
    float thn  = ftanh(hn);                                                  \
    T_WR[row] = thn;                                                         \
    oh[(SIDX) * NH + row] = hn;                                              \
    float pzs = wave_sum_lane63(thn * w_hz);                                 \
    if (lane == 63) red[RWR][wid] = pzs;                                     \
    asm volatile("s_waitcnt lgkmcnt(0)\n\ts_barrier" ::: "memory");          \
    float4 r0 = *(const float4*)&red[RWR][0];                                \
    float4 r1 = *(const float4*)&red[RWR][4];                                \
    float z = ((r0.x + r0.y) + (r0.z + r0.w)) + ((r1.x + r1.y) + (r1.z + r1.w)); \
    if (p == 0) oz[SIDX] = z;                                                \
    z_prev = z; h = hn;                                                      \
  }

__global__ __launch_bounds__(512, 1) void esn_steps(
    const float* __restrict__ x,   const float* __restrict__ h0,
    const float* __restrict__ Wih, const float* __restrict__ Whz,
    const float* __restrict__ Wzh, const float* __restrict__ vals,
    const unsigned* __restrict__ offs, const int* __restrict__ perm,
    const int* __restrict__ cntw, float* __restrict__ out) {
  __shared__ float t_lds[2][NH];              // tanh(h), double-buffered
  __shared__ float x_lds[TT];                 // this batch's input row
  __shared__ __align__(16) float red[2][8];   // cross-wave partials for z

  const int p    = threadIdx.x;               // sorted position owned
  const int b    = blockIdx.x;
  const int lane = p & 63;
  const int wid  = p >> 6;
  const int row  = perm[p];                   // actual hidden unit

  float* t0 = t_lds[0];
  float* t1 = t_lds[1];

  for (int i = p; i < TT; i += NH) x_lds[i] = x[(size_t)b * TT + i];

  int cw = __builtin_amdgcn_readfirstlane((cntw[wid] + 3) & ~3);

  float    wval[PAD];
  unsigned cidx[PAD];
  #pragma unroll
  for (int e = 0; e < PAD; ++e) {
    wval[e] = vals[e * NH + p];
    cidx[e] = offs[e * NH + p] * 4u;
  }
  #pragma unroll
  for (int e = 0; e < PIN; ++e)
    asm volatile("" : "+v"(wval[e]), "+v"(cidx[e]));

  const float w_ih = Wih[row];
  const float w_hz = Whz[row];
  const float w_zh = Wzh[row];
  float h = h0[(size_t)b * NH + row];

  float* oz = out + (size_t)b * TT;                        // z region [B,T,1]
  float* oh = out + (size_t)BB * TT + (size_t)b * TT * NH; // h region [B,T,NH]

  float th0 = ftanh(h);
  t0[row] = th0;
  float pz = wave_sum_lane63(th0 * w_hz);
  if (lane == 63) red[0][wid] = pz;
  __syncthreads();
  float4 i0 = *(const float4*)&red[0][0];
  float4 i1 = *(const float4*)&red[0][4];
  float z_prev = ((i0.x + i0.y) + (i0.z + i0.w)) + ((i1.x + i1.y) + (i1.z + i1.w));

  for (int s = 0; s < TT; s += 2) {
    ESN_STEP(t0, t1, 1, s);
    ESN_STEP(t1, t0, 0, s + 1);
  }
}

// ---------------------------------------------------------------------------
extern "C" void kernel_launch(void* const* d_in, const int* in_sizes, int n_in,
                              void* d_out, int out_size, void* d_ws,
                              size_t ws_size, hipStream_t stream) {
  const float* x   = (const float*)d_in[0];
  const float* h0  = (const float*)d_in[1];
  const float* Wih = (const float*)d_in[2];
  const float* Whh = (const float*)d_in[3];
  const float* Whz = (const float*)d_in[4];
  const float* Wzh = (const float*)d_in[5];
  float* out = (float*)d_out;

  float*    vals = (float*)d_ws;                     // PAD*NH f32 = 192 KB
  unsigned* offs = (unsigned*)(vals + PAD * NH);     // PAD*NH u32 = 192 KB
  int*      nnz  = (int*)(offs + PAD * NH);          // NH
  int*      perm = nnz + NH;                         // NH
  int*      cntw = perm + NH;                        // 8

  hipLaunchKernelGGL(count_nnz, dim3(NH / 8), dim3(512), 0, stream, Whh, nnz);
  hipLaunchKernelGGL(sort_rows, dim3(1), dim3(512), 0, stream, nnz, perm);
  hipLaunchKernelGGL(build_sched, dim3(8), dim3(64), 0, stream,
                     Whh, perm, vals, offs, cntw);
  hipLaunchKernelGGL(esn_steps, dim3(BB), dim3(512), 0, stream,
                     x, h0, Wih, Whz, Wzh, vals, offs, perm, cntw, out);
}